// Round 5
// baseline (31.650 us; speedup 1.0000x reference)
//
#include <hip/hip_runtime.h>

#define BS 2048
#define DIM 256
#define MARGIN_F 0.3f

typedef __attribute__((ext_vector_type(4))) float f32x4;
typedef __attribute__((ext_vector_type(2))) __fp16 fp16x2;   // cvt_pkrtz return type
typedef __attribute__((ext_vector_type(8))) _Float16 f16x8;  // MFMA operand type

union HU { fp16x2 h2[4]; f16x8 h8; };

// Kernel 1: per-row norms (exact fp32), 1 wave per row, float4 loads, shfl-only.
// Also zeroes d_out (runs stream-ordered before tl_wave's atomics).
__global__ __launch_bounds__(256) void tl_norms(const float* __restrict__ sketch,
                                                const float* __restrict__ photo,
                                                float* __restrict__ sn,
                                                float* __restrict__ pn,
                                                float* __restrict__ pos,
                                                float* __restrict__ out) {
    const int t = threadIdx.x;
    const int w = t >> 6, lane = t & 63;
    const int row = blockIdx.x * 4 + w;
    const float4 s4 = *reinterpret_cast<const float4*>(&sketch[(size_t)row * DIM + lane * 4]);
    const float4 p4 = *reinterpret_cast<const float4*>(&photo [(size_t)row * DIM + lane * 4]);
    float vs = s4.x * s4.x + s4.y * s4.y + s4.z * s4.z + s4.w * s4.w;
    float vp = p4.x * p4.x + p4.y * p4.y + p4.z * p4.z + p4.w * p4.w;
    float dx = s4.x - p4.x, dy = s4.y - p4.y, dz = s4.z - p4.z, dw = s4.w - p4.w;
    float vd = dx * dx + dy * dy + dz * dz + dw * dw;
    #pragma unroll
    for (int off = 32; off > 0; off >>= 1) {
        vs += __shfl_down(vs, off);
        vp += __shfl_down(vp, off);
        vd += __shfl_down(vd, off);
    }
    if (lane == 0) { sn[row] = vs; pn[row] = vp; pos[row] = sqrtf(vd); }
    if (blockIdx.x == 0 && t == 0) out[0] = 0.0f;
}

// Kernel 2: LDS-free MFMA cross-GEMM. Each WAVE owns an independent 64x64
// output tile = 4x4 fragments of mfma_f32_16x16x32_f16 over K=256 (8 k-steps).
// Fragments load directly global(fp32, L2-resident) -> cvt_pkrtz -> MFMA.
// No barriers / LDS in the main loop; MLP (16 loads in flight) hides latency.
// Block = 4 waves covering 128x128 (waves share A-rows / B-rows via L1/L2).
__global__ __launch_bounds__(256) void tl_wave(const float* __restrict__ photo,
                                               const float* __restrict__ sketch,
                                               const float* __restrict__ sn,
                                               const float* __restrict__ pn,
                                               const float* __restrict__ pos,
                                               float* __restrict__ out) {
    const int t = threadIdx.x;
    const int w = t >> 6, lane = t & 63;
    const int i0 = blockIdx.y * 128 + (w >> 1) * 64;   // wave's i origin (photo)
    const int j0 = blockIdx.x * 128 + (w & 1) * 64;    // wave's j origin (sketch)
    const int r16 = lane & 15, g = lane >> 4;          // fragment lane decomposition

    f32x4 acc[4][4] = {};

    // One base pointer per fragment row; k-steps fold into immediate offsets.
    const float* pa0 = &photo [(size_t)(i0 +  0 + r16) * DIM + g * 8];
    const float* pa1 = &photo [(size_t)(i0 + 16 + r16) * DIM + g * 8];
    const float* pa2 = &photo [(size_t)(i0 + 32 + r16) * DIM + g * 8];
    const float* pa3 = &photo [(size_t)(i0 + 48 + r16) * DIM + g * 8];
    const float* pb0 = &sketch[(size_t)(j0 +  0 + r16) * DIM + g * 8];
    const float* pb1 = &sketch[(size_t)(j0 + 16 + r16) * DIM + g * 8];
    const float* pb2 = &sketch[(size_t)(j0 + 32 + r16) * DIM + g * 8];
    const float* pb3 = &sketch[(size_t)(j0 + 48 + r16) * DIM + g * 8];
    const float* pA[4] = { pa0, pa1, pa2, pa3 };
    const float* pB[4] = { pb0, pb1, pb2, pb3 };

    #pragma unroll
    for (int kt = 0; kt < DIM / 32; ++kt) {
        f16x8 af[4], bf[4];
        #pragma unroll
        for (int m = 0; m < 4; ++m) {
            const float4 x0 = *reinterpret_cast<const float4*>(pA[m] + kt * 32);
            const float4 x1 = *reinterpret_cast<const float4*>(pA[m] + kt * 32 + 4);
            HU u;
            u.h2[0] = __builtin_amdgcn_cvt_pkrtz(x0.x, x0.y);
            u.h2[1] = __builtin_amdgcn_cvt_pkrtz(x0.z, x0.w);
            u.h2[2] = __builtin_amdgcn_cvt_pkrtz(x1.x, x1.y);
            u.h2[3] = __builtin_amdgcn_cvt_pkrtz(x1.z, x1.w);
            af[m] = u.h8;
            const float4 y0 = *reinterpret_cast<const float4*>(pB[m] + kt * 32);
            const float4 y1 = *reinterpret_cast<const float4*>(pB[m] + kt * 32 + 4);
            HU v;
            v.h2[0] = __builtin_amdgcn_cvt_pkrtz(y0.x, y0.y);
            v.h2[1] = __builtin_amdgcn_cvt_pkrtz(y0.z, y0.w);
            v.h2[2] = __builtin_amdgcn_cvt_pkrtz(y1.x, y1.y);
            v.h2[3] = __builtin_amdgcn_cvt_pkrtz(y1.z, y1.w);
            bf[m] = v.h8;
        }
        #pragma unroll
        for (int m = 0; m < 4; ++m)
            #pragma unroll
            for (int n = 0; n < 4; ++n)
                acc[m][n] = __builtin_amdgcn_mfma_f32_16x16x32_f16(af[m], bf[n], acc[m][n], 0, 0, 0);
    }

    // Fused epilogue. C/D layout (HW-verified r2/r4): col = lane&15 (j),
    // row = (lane>>4)*4 + reg (i).
    const int jl = r16;
    const int rl = g * 4;

    float partial = 0.0f;
    #pragma unroll
    for (int n = 0; n < 4; ++n) {
        const int j = j0 + n * 16 + jl;
        const float snj = sn[j];
        const float posj = pos[j];
        #pragma unroll
        for (int m = 0; m < 4; ++m) {
            const int ibase = i0 + m * 16 + rl;
            #pragma unroll
            for (int r = 0; r < 4; ++r) {
                const int i = ibase + r;
                const float c = acc[m][n][r];
                float neg2 = fmaxf(pn[i] + snj - 2.0f * c, 0.0f);
                float tl = posj - sqrtf(neg2) + MARGIN_F;
                partial += (i != j) ? fmaxf(tl, 0.0f) : 0.0f;
            }
        }
    }

    // Wave reduce -> block reduce -> one scaled atomicAdd per block.
    #pragma unroll
    for (int off = 32; off > 0; off >>= 1) partial += __shfl_down(partial, off);
    __shared__ float lsum[4];
    if (lane == 0) lsum[w] = partial;
    __syncthreads();
    if (t == 0) {
        float s = lsum[0] + lsum[1] + lsum[2] + lsum[3];
        atomicAdd(out, s * (1.0f / ((float)BS * (float)BS)));
    }
}

extern "C" void kernel_launch(void* const* d_in, const int* in_sizes, int n_in,
                              void* d_out, int out_size, void* d_ws, size_t ws_size,
                              hipStream_t stream) {
    const float* sketch = (const float*)d_in[0];
    const float* photo  = (const float*)d_in[1];
    float* out = (float*)d_out;

    float* sn  = (float*)d_ws;        // BS floats
    float* pn  = sn + BS;             // BS floats
    float* pos = pn + BS;             // BS floats

    // tl_norms zeroes d_out (runs before tl_wave's atomics in stream order).
    tl_norms<<<dim3(BS / 4), dim3(256), 0, stream>>>(sketch, photo, sn, pn, pos, out);

    dim3 grid(BS / 128, BS / 128);   // 16 x 16 = 256 blocks, 4 wave-tiles each
    tl_wave<<<grid, dim3(256), 0, stream>>>(photo, sketch, sn, pn, pos, out);
}

// Round 6
// 29.055 us; speedup vs baseline: 1.0893x; 1.0893x over previous
//
#include <hip/hip_runtime.h>

#define BS 2048
#define DIM 256
#define MARGIN_F 0.3f
#define BK 128
#define PADH 8
#define LDW (BK + PADH)   // LDS row stride in halves: 136 (272 B = 68 banks == 4 mod 32)

typedef __attribute__((ext_vector_type(4))) float f32x4;
typedef __attribute__((ext_vector_type(2))) __fp16 fp16x2;   // cvt_pkrtz return type
typedef __attribute__((ext_vector_type(8))) _Float16 f16x8;  // MFMA operand type

// Kernel 1: fused norms + fp32->fp16 pre-convert. One wave per row; lane owns
// 4 consecutive floats of each input row. Norms exact fp32 (matches ref);
// fp16 copies (RTZ) feed the MFMA GEMM. Also zeroes d_out.
__global__ __launch_bounds__(256) void tl_prep(const float* __restrict__ sketch,
                                               const float* __restrict__ photo,
                                               float* __restrict__ sn,
                                               float* __restrict__ pn,
                                               float* __restrict__ pos,
                                               _Float16* __restrict__ hs,   // sketch fp16
                                               _Float16* __restrict__ hp,   // photo  fp16
                                               float* __restrict__ out) {
    const int t = threadIdx.x;
    const int w = t >> 6, lane = t & 63;
    const int row = blockIdx.x * 4 + w;
    const float4 s4 = *reinterpret_cast<const float4*>(&sketch[(size_t)row * DIM + lane * 4]);
    const float4 p4 = *reinterpret_cast<const float4*>(&photo [(size_t)row * DIM + lane * 4]);

    float vs = s4.x * s4.x + s4.y * s4.y + s4.z * s4.z + s4.w * s4.w;
    float vp = p4.x * p4.x + p4.y * p4.y + p4.z * p4.z + p4.w * p4.w;
    float dx = s4.x - p4.x, dy = s4.y - p4.y, dz = s4.z - p4.z, dw = s4.w - p4.w;
    float vd = dx * dx + dy * dy + dz * dz + dw * dw;
    #pragma unroll
    for (int off = 32; off > 0; off >>= 1) {
        vs += __shfl_down(vs, off);
        vp += __shfl_down(vp, off);
        vd += __shfl_down(vd, off);
    }
    if (lane == 0) { sn[row] = vs; pn[row] = vp; pos[row] = sqrtf(vd); }

    union { fp16x2 h2[2]; uint2 u; } cs, cp;
    cs.h2[0] = __builtin_amdgcn_cvt_pkrtz(s4.x, s4.y);
    cs.h2[1] = __builtin_amdgcn_cvt_pkrtz(s4.z, s4.w);
    cp.h2[0] = __builtin_amdgcn_cvt_pkrtz(p4.x, p4.y);
    cp.h2[1] = __builtin_amdgcn_cvt_pkrtz(p4.z, p4.w);
    *reinterpret_cast<uint2*>(&hs[(size_t)row * DIM + lane * 4]) = cs.u;
    *reinterpret_cast<uint2*>(&hp[(size_t)row * DIM + lane * 4]) = cp.u;

    if (blockIdx.x == 0 && t == 0) out[0] = 0.0f;
}

// Kernel 2: fp16 MFMA cross-GEMM + fused epilogue. 64x64 tile / 256-thread
// block (4 waves, each 32x32 = 2x2 frags of 16x16x32_f16). BK=128, LDS 34 KB
// -> 4 blocks/CU resident (4 waves/SIMD TLP). Staging is contiguous 64 B/thread
// row-stream reads of the fp16 copies (L2-resident), no converts in-loop.
__global__ __launch_bounds__(256) void tl_gemm(const _Float16* __restrict__ hp,  // photo (i)
                                               const _Float16* __restrict__ hs,  // sketch (j)
                                               const float* __restrict__ sn,
                                               const float* __restrict__ pn,
                                               const float* __restrict__ pos,
                                               float* __restrict__ out) {
    __shared__ _Float16 As[64][LDW];  // photo rows (i)
    __shared__ _Float16 Bs[64][LDW];  // sketch rows (j)

    const int t = threadIdx.x;
    const int i0 = blockIdx.y * 64;
    const int j0 = blockIdx.x * 64;
    const int w = t >> 6, lane = t & 63;
    const int wr = (w >> 1) * 32;   // wave row offset in tile
    const int wc = (w & 1) * 32;    // wave col offset in tile
    const int r16 = lane & 15, g = lane >> 4;

    f32x4 acc[2][2] = {};

    const int sr = t >> 2;          // staging row 0..63
    const int sq = (t & 3) * 32;    // staging col in halves (32 halves = 64 B)

    for (int k0 = 0; k0 < DIM; k0 += BK) {
        // ---- stage 64 rows x 128 halves per operand, 4x ds_write_b128 each
        {
            const uint4* ga = reinterpret_cast<const uint4*>(&hp[(size_t)(i0 + sr) * DIM + k0 + sq]);
            const uint4* gb = reinterpret_cast<const uint4*>(&hs[(size_t)(j0 + sr) * DIM + k0 + sq]);
            uint4 a0 = ga[0], a1 = ga[1], a2 = ga[2], a3 = ga[3];
            uint4 b0 = gb[0], b1 = gb[1], b2 = gb[2], b3 = gb[3];
            *reinterpret_cast<uint4*>(&As[sr][sq])      = a0;
            *reinterpret_cast<uint4*>(&As[sr][sq + 8])  = a1;
            *reinterpret_cast<uint4*>(&As[sr][sq + 16]) = a2;
            *reinterpret_cast<uint4*>(&As[sr][sq + 24]) = a3;
            *reinterpret_cast<uint4*>(&Bs[sr][sq])      = b0;
            *reinterpret_cast<uint4*>(&Bs[sr][sq + 8])  = b1;
            *reinterpret_cast<uint4*>(&Bs[sr][sq + 16]) = b2;
            *reinterpret_cast<uint4*>(&Bs[sr][sq + 24]) = b3;
        }
        __syncthreads();
        // ---- MFMA: 4 k-slices of 32, 2x2 fragments each
        #pragma unroll
        for (int ks = 0; ks < BK / 32; ++ks) {
            const int kk = ks * 32 + g * 8;
            f16x8 af[2], bf[2];
            #pragma unroll
            for (int m = 0; m < 2; ++m)
                af[m] = *reinterpret_cast<const f16x8*>(&As[wr + m * 16 + r16][kk]);
            #pragma unroll
            for (int n = 0; n < 2; ++n)
                bf[n] = *reinterpret_cast<const f16x8*>(&Bs[wc + n * 16 + r16][kk]);
            #pragma unroll
            for (int m = 0; m < 2; ++m)
                #pragma unroll
                for (int n = 0; n < 2; ++n)
                    acc[m][n] = __builtin_amdgcn_mfma_f32_16x16x32_f16(af[m], bf[n], acc[m][n], 0, 0, 0);
        }
        __syncthreads();
    }

    // Fused epilogue (verified r2/r4/r5). C/D: col = lane&15 (j), row = g*4+reg (i).
    const int jl = r16;
    const int rl = g * 4;

    float partial = 0.0f;
    #pragma unroll
    for (int n = 0; n < 2; ++n) {
        const int j = j0 + wc + n * 16 + jl;
        const float snj = sn[j];
        const float posj = pos[j];
        #pragma unroll
        for (int m = 0; m < 2; ++m) {
            const int ibase = i0 + wr + m * 16 + rl;
            #pragma unroll
            for (int r = 0; r < 4; ++r) {
                const int i = ibase + r;
                const float c = acc[m][n][r];
                float neg2 = fmaxf(pn[i] + snj - 2.0f * c, 0.0f);
                float tl = posj - sqrtf(neg2) + MARGIN_F;
                partial += (i != j) ? fmaxf(tl, 0.0f) : 0.0f;
            }
        }
    }

    // Wave reduce -> block reduce -> one scaled atomicAdd per block.
    #pragma unroll
    for (int off = 32; off > 0; off >>= 1) partial += __shfl_down(partial, off);
    __shared__ float lsum[4];
    if (lane == 0) lsum[w] = partial;
    __syncthreads();
    if (t == 0) {
        float s = lsum[0] + lsum[1] + lsum[2] + lsum[3];
        atomicAdd(out, s * (1.0f / ((float)BS * (float)BS)));
    }
}

extern "C" void kernel_launch(void* const* d_in, const int* in_sizes, int n_in,
                              void* d_out, int out_size, void* d_ws, size_t ws_size,
                              hipStream_t stream) {
    const float* sketch = (const float*)d_in[0];
    const float* photo  = (const float*)d_in[1];
    float* out = (float*)d_out;

    float* sn  = (float*)d_ws;            // BS floats
    float* pn  = sn + BS;                 // BS floats
    float* pos = pn + BS;                 // BS floats
    _Float16* hp = (_Float16*)(pos + BS); // BS*DIM halves (photo fp16)
    _Float16* hs = hp + (size_t)BS * DIM; // BS*DIM halves (sketch fp16)

    // tl_prep zeroes d_out and writes sn/pn/pos + fp16 copies.
    tl_prep<<<dim3(BS / 4), dim3(256), 0, stream>>>(sketch, photo, sn, pn, pos, hs, hp, out);

    dim3 grid(BS / 64, BS / 64);   // 32 x 32 = 1024 blocks, 4 blocks/CU resident
    tl_gemm<<<grid, dim3(256), 0, stream>>>(hp, hs, sn, pn, pos, out);
}

// Round 7
// 28.337 us; speedup vs baseline: 1.1169x; 1.0253x over previous
//
#include <hip/hip_runtime.h>

#define BS 2048
#define DIM 256
#define MARGIN_F 0.3f

typedef __attribute__((ext_vector_type(4))) float f32x4;
typedef __attribute__((ext_vector_type(2))) __fp16 fp16x2;   // cvt_pkrtz return type
typedef __attribute__((ext_vector_type(8))) _Float16 f16x8;  // MFMA operand type

// Async global->LDS direct load, 16 B per lane (global_load_lds_dwordx4).
// LDS dest is wave-uniform base + lane*16 (m104); global src is per-lane.
__device__ __forceinline__ void gload_lds16(const void* g, void* l) {
    __builtin_amdgcn_global_load_lds((const __attribute__((address_space(1))) void*)g,
                                     (__attribute__((address_space(3))) void*)l,
                                     16, 0, 0);
}

// Kernel 1: fused norms + fp32->fp16 pre-convert with PRE-SWIZZLED layout.
// Within each 128 B window of a row, 16 B chunk q is stored at q ^ (row&7).
// (Involution; tl_gemm's ds_read applies the same XOR to recover chunk q.)
// Norms exact fp32. Also zeroes d_out.
__global__ __launch_bounds__(256) void tl_prep(const float* __restrict__ sketch,
                                               const float* __restrict__ photo,
                                               float* __restrict__ sn,
                                               float* __restrict__ pn,
                                               float* __restrict__ pos,
                                               _Float16* __restrict__ hs,   // sketch fp16 (swizzled)
                                               _Float16* __restrict__ hp,   // photo  fp16 (swizzled)
                                               float* __restrict__ out) {
    const int t = threadIdx.x;
    const int w = t >> 6, lane = t & 63;
    const int row = blockIdx.x * 4 + w;
    const float4 s4 = *reinterpret_cast<const float4*>(&sketch[(size_t)row * DIM + lane * 4]);
    const float4 p4 = *reinterpret_cast<const float4*>(&photo [(size_t)row * DIM + lane * 4]);

    float vs = s4.x * s4.x + s4.y * s4.y + s4.z * s4.z + s4.w * s4.w;
    float vp = p4.x * p4.x + p4.y * p4.y + p4.z * p4.z + p4.w * p4.w;
    float dx = s4.x - p4.x, dy = s4.y - p4.y, dz = s4.z - p4.z, dw = s4.w - p4.w;
    float vd = dx * dx + dy * dy + dz * dz + dw * dw;
    #pragma unroll
    for (int off = 32; off > 0; off >>= 1) {
        vs += __shfl_down(vs, off);
        vp += __shfl_down(vp, off);
        vd += __shfl_down(vd, off);
    }
    if (lane == 0) { sn[row] = vs; pn[row] = vp; pos[row] = sqrtf(vd); }

    union { fp16x2 h2[2]; uint2 u; } cs, cp;
    cs.h2[0] = __builtin_amdgcn_cvt_pkrtz(s4.x, s4.y);
    cs.h2[1] = __builtin_amdgcn_cvt_pkrtz(s4.z, s4.w);
    cp.h2[0] = __builtin_amdgcn_cvt_pkrtz(p4.x, p4.y);
    cp.h2[1] = __builtin_amdgcn_cvt_pkrtz(p4.z, p4.w);
    // Lane holds orig halves [4*lane, 4*lane+4): 16B chunk qg = lane>>1,
    // half-of-chunk = lane&1. Swizzled position keeps the window (qg&24),
    // XORs the low 3 bits with row&7.
    const int qg = lane >> 1;
    const int pg = (qg & 24) | ((qg & 7) ^ (row & 7));
    const size_t dsth = (size_t)row * DIM + pg * 8 + (lane & 1) * 4;
    *reinterpret_cast<uint2*>(&hs[dsth]) = cs.u;
    *reinterpret_cast<uint2*>(&hp[dsth]) = cp.u;

    if (blockIdx.x == 0 && t == 0) out[0] = 0.0f;
}

// Kernel 2: fp16 MFMA cross-GEMM with global_load_lds staging + fused epilogue.
// 64x64 tile / 256-thread block (4 waves, each 32x32 = 2x2 frags of 16x16x32).
// BK=64 halves, unpadded LDS 16 KB. Per K-step per wave: 4 async 1KB
// global_load_lds_dwordx4 (no ds_write, no VGPR round-trip), barrier,
// 8 ds_read_b128 (XOR-deswizzled, conflict-free) + 8 MFMA, barrier.
__global__ __launch_bounds__(256) void tl_gemm(const _Float16* __restrict__ hp,  // photo (i), swizzled
                                               const _Float16* __restrict__ hs,  // sketch (j), swizzled
                                               const float* __restrict__ sn,
                                               const float* __restrict__ pn,
                                               const float* __restrict__ pos,
                                               float* __restrict__ out) {
    __shared__ _Float16 As[64][64];  // photo rows (i), one 64-half K-window
    __shared__ _Float16 Bs[64][64];  // sketch rows (j)

    const int t = threadIdx.x;
    const int i0 = blockIdx.y * 64;
    const int j0 = blockIdx.x * 64;
    const int w = t >> 6, lane = t & 63;
    const int wr = (w >> 1) * 32;   // wave row offset in tile
    const int wc = (w & 1) * 32;    // wave col offset in tile
    const int r16 = lane & 15, g = lane >> 4;

    f32x4 acc[2][2] = {};

    // Wave w stages rows [w*16, w*16+16) of both operands: 2 instrs each
    // (8 rows per 1KB instr: lane -> row lane>>3, chunk lane&7).
    const int srow = w * 16 + (lane >> 3);
    const int sch  = lane & 7;
    const _Float16* gA0 = &hp[(size_t)(i0 + srow) * DIM + sch * 8];
    const _Float16* gB0 = &hs[(size_t)(j0 + srow) * DIM + sch * 8];
    const _Float16* gA1 = gA0 + 8 * DIM;
    const _Float16* gB1 = gB0 + 8 * DIM;
    _Float16* lA0 = &As[w * 16][0];      // wave-uniform LDS bases
    _Float16* lA1 = &As[w * 16 + 8][0];
    _Float16* lB0 = &Bs[w * 16][0];
    _Float16* lB1 = &Bs[w * 16 + 8][0];

    for (int kw = 0; kw < 4; ++kw) {     // K-window: 64 halves each
        const int koff = kw * 64;        // halves
        gload_lds16(gA0 + koff, lA0);
        gload_lds16(gA1 + koff, lA1);
        gload_lds16(gB0 + koff, lB0);
        gload_lds16(gB1 + koff, lB1);
        __syncthreads();                 // drains vmcnt (gl_lds tracked there)
        #pragma unroll
        for (int ks = 0; ks < 2; ++ks) {
            const int q = ks * 4 + g;    // orig 16B-chunk index within window
            f16x8 af[2], bf[2];
            #pragma unroll
            for (int m = 0; m < 2; ++m) {
                const int r = wr + m * 16 + r16;
                af[m] = *reinterpret_cast<const f16x8*>(&As[r][(q ^ (r16 & 7)) * 8]);
            }
            #pragma unroll
            for (int n = 0; n < 2; ++n) {
                const int r = wc + n * 16 + r16;
                bf[n] = *reinterpret_cast<const f16x8*>(&Bs[r][(q ^ (r16 & 7)) * 8]);
            }
            #pragma unroll
            for (int m = 0; m < 2; ++m)
                #pragma unroll
                for (int n = 0; n < 2; ++n)
                    acc[m][n] = __builtin_amdgcn_mfma_f32_16x16x32_f16(af[m], bf[n], acc[m][n], 0, 0, 0);
        }
        __syncthreads();
    }

    // Fused epilogue (verified r2/r4/r5/r6). C/D: col = lane&15 (j), row = g*4+reg (i).
    const int jl = r16;
    const int rl = g * 4;

    float partial = 0.0f;
    #pragma unroll
    for (int n = 0; n < 2; ++n) {
        const int j = j0 + wc + n * 16 + jl;
        const float snj = sn[j];
        const float posj = pos[j];
        #pragma unroll
        for (int m = 0; m < 2; ++m) {
            const int ibase = i0 + wr + m * 16 + rl;
            #pragma unroll
            for (int r = 0; r < 4; ++r) {
                const int i = ibase + r;
                const float c = acc[m][n][r];
                float neg2 = fmaxf(pn[i] + snj - 2.0f * c, 0.0f);
                float tl = posj - sqrtf(neg2) + MARGIN_F;
                partial += (i != j) ? fmaxf(tl, 0.0f) : 0.0f;
            }
        }
    }

    // Wave reduce -> block reduce -> one scaled atomicAdd per block.
    #pragma unroll
    for (int off = 32; off > 0; off >>= 1) partial += __shfl_down(partial, off);
    __shared__ float lsum[4];
    if (lane == 0) lsum[w] = partial;
    __syncthreads();
    if (t == 0) {
        float s = lsum[0] + lsum[1] + lsum[2] + lsum[3];
        atomicAdd(out, s * (1.0f / ((float)BS * (float)BS)));
    }
}

extern "C" void kernel_launch(void* const* d_in, const int* in_sizes, int n_in,
                              void* d_out, int out_size, void* d_ws, size_t ws_size,
                              hipStream_t stream) {
    const float* sketch = (const float*)d_in[0];
    const float* photo  = (const float*)d_in[1];
    float* out = (float*)d_out;

    float* sn  = (float*)d_ws;            // BS floats
    float* pn  = sn + BS;                 // BS floats
    float* pos = pn + BS;                 // BS floats
    _Float16* hp = (_Float16*)(pos + BS); // BS*DIM halves (photo fp16, swizzled)
    _Float16* hs = hp + (size_t)BS * DIM; // BS*DIM halves (sketch fp16, swizzled)

    // tl_prep zeroes d_out and writes sn/pn/pos + swizzled fp16 copies.
    tl_prep<<<dim3(BS / 4), dim3(256), 0, stream>>>(sketch, photo, sn, pn, pos, hs, hp, out);

    dim3 grid(BS / 64, BS / 64);   // 32 x 32 = 1024 blocks
    tl_gemm<<<grid, dim3(256), 0, stream>>>(hp, hs, sn, pn, pos, out);
}